// Round 13
// baseline (316.820 us; speedup 1.0000x reference)
//
#include <hip/hip_runtime.h>

#define BN_EPS 0.001f
#define CAP 32    // deg = 1 + Poisson(~9); P(deg >= 32) ~ 1e-22 -> safe
#define NPART 8   // node partitions, bound to XCD via p = blockIdx&7 (heuristic)
#define SEGE 4096 // edges per scatter segment (256 threads x 16 edges)
#define ABLK 8    // agg: nodes per block (1 node per 32-lane group)

typedef __attribute__((ext_vector_type(8))) short bf16x8;
typedef __attribute__((ext_vector_type(4))) float f32x4;

__device__ __forceinline__ unsigned short f2bf(float f) {
  unsigned u = __float_as_uint(f);
  u += 0x7fffu + ((u >> 16) & 1u);
  return (unsigned short)(u >> 16);
}
__device__ __forceinline__ float bfLO(unsigned u) { return __uint_as_float(u << 16); }
__device__ __forceinline__ float bfHI(unsigned u) { return __uint_as_float(u & 0xffff0000u); }

// ---------- FUSED, TEMPORALLY SPLIT: gemm blocks first, scatter gated behind ----------
// Gemm blocks (bid < Gg) stream X (~10us BW-bound) and bump a done-counter.
// Scatter blocks spin on it with a BOUNDED timeout (perf heuristic only, no data
// dependency -> G16-safe): scatter then runs with X-stream gone, so its 1.6MB/XCD
// partition hot-set actually stays L2-resident (the residual ~33MB write-amp was
// X-capacity-transit evicting dirty ell lines between partial writes).
__global__ __launch_bounds__(256) void k_fused(
    const float* __restrict__ X, const float* __restrict__ W,
    const float* __restrict__ B, unsigned short* __restrict__ hb, int N, int Gg,
    const int2* __restrict__ ei, int* __restrict__ cnt,
    int* __restrict__ ell_t, int E, int gemmPad, int* __restrict__ flag) {
  __shared__ float WtF[4096];  // 16 KB: Wt[col][k] bf16, XOR-swizzled

  int bid = blockIdx.x;
  int tid = threadIdx.x;

  if (bid >= gemmPad) {
    // ----- scatter role: partition p = bid&7 (XCD-bound), segment = (bid-gemmPad)>>3 -----
    int p = bid & 7;
    int seg = (bid - gemmPad) >> 3;
    // gate: wait for gemm completion (bounded ~40us; timeout -> proceed, perf-only)
    if (tid == 0) {
      int spins = 0;
      while (__hip_atomic_load(flag, __ATOMIC_RELAXED, __HIP_MEMORY_SCOPE_AGENT) < Gg
             && spins < 192) {
        __builtin_amdgcn_s_sleep(8);
        ++spins;
      }
    }
    __syncthreads();

    int lo = (int)((long long)p * N / NPART);
    int hi = (int)((long long)(p + 1) * N / NPART);
    const int4* e4 = (const int4*)ei;
    int n4 = E >> 1;
    int base4 = seg * (SEGE / 2);
    #pragma unroll
    for (int i = 0; i < 8; ++i) {
      int q = base4 + i * 256 + tid;
      if (q < n4) {
        int4 v = e4[q];                   // 2 edges, coalesced
        if (v.x >= lo && v.x < hi) {
          int pos = atomicAdd(&cnt[v.x], 1);
          if (pos < CAP) ell_t[(size_t)pos * N + v.x] = v.y;
        }
        if (v.z >= lo && v.z < hi) {
          int pos = atomicAdd(&cnt[v.z], 1);
          if (pos < CAP) ell_t[(size_t)pos * N + v.z] = v.w;
        }
      }
    }
    if ((E & 1) && seg == 0 && tid == 0) {
      int2 sd = ei[E - 1];
      if (sd.x >= lo && sd.x < hi) {
        int pos = atomicAdd(&cnt[sd.x], 1);
        if (pos < CAP) ell_t[(size_t)pos * N + sd.x] = sd.y;
      }
    }
    return;
  }

  if (bid >= Gg) return;   // pad blocks between Gg and gemmPad: idle

  // ----- gemm role: hb = bf16(X@W + b) via MFMA, 64 rows x 64 cols per block -----
  int tile = bid;

  char* Wt = (char*)WtF;
  const float4* W4 = (const float4*)W;
  for (int i = tid; i < 2048; i += 256) {
    float4 v = W4[i];
    int k = i >> 4;
    int col0 = (i & 15) << 2;
    int kb2 = k << 1;
    *(unsigned short*)(Wt + (((col0 + 0) << 8) | (kb2 ^ (((col0 + 0) & 7) << 4)))) = f2bf(v.x);
    *(unsigned short*)(Wt + (((col0 + 1) << 8) | (kb2 ^ (((col0 + 1) & 7) << 4)))) = f2bf(v.y);
    *(unsigned short*)(Wt + (((col0 + 2) << 8) | (kb2 ^ (((col0 + 2) & 7) << 4)))) = f2bf(v.z);
    *(unsigned short*)(Wt + (((col0 + 3) << 8) | (kb2 ^ (((col0 + 3) & 7) << 4)))) = f2bf(v.w);
  }
  __syncthreads();

  int lane = tid & 63;
  int w = tid >> 6;
  int l15 = lane & 15;
  int lk = lane >> 4;

  int row0 = tile * 64;
  int rA = row0 + w * 16 + l15;
  bool rowok = rA < N;
  const float* xp = X + (size_t)rA * 128 + (lk << 3);

  f32x4 acc[4];
  #pragma unroll
  for (int n = 0; n < 4; ++n) {
    float bv = B[(n << 4) + l15];
    acc[n] = (f32x4){bv, bv, bv, bv};
  }

  #pragma unroll
  for (int kb = 0; kb < 4; ++kb) {
    bf16x8 af = {0, 0, 0, 0, 0, 0, 0, 0};
    if (rowok) {
      float4 x0 = *(const float4*)(xp + kb * 32);
      float4 x1 = *(const float4*)(xp + kb * 32 + 4);
      af[0] = (short)f2bf(x0.x); af[1] = (short)f2bf(x0.y);
      af[2] = (short)f2bf(x0.z); af[3] = (short)f2bf(x0.w);
      af[4] = (short)f2bf(x1.x); af[5] = (short)f2bf(x1.y);
      af[6] = (short)f2bf(x1.z); af[7] = (short)f2bf(x1.w);
    }
    int kbyte = (kb << 6) | (lk << 4);
    #pragma unroll
    for (int n = 0; n < 4; ++n) {
      int col = (n << 4) + l15;
      bf16x8 bfr = *(const bf16x8*)(Wt + ((col << 8) | (kbyte ^ ((col & 7) << 4))));
      acc[n] = __builtin_amdgcn_mfma_f32_16x16x32_bf16(af, bfr, acc[n], 0, 0, 0);
    }
  }

  // C/D layout (verified m89/m91): col = lane&15, row = (lane>>4)*4 + reg
  int rbase = row0 + w * 16 + (lk << 2);
  #pragma unroll
  for (int n = 0; n < 4; ++n) {
    #pragma unroll
    for (int q = 0; q < 4; ++q) {
      int row = rbase + q;
      if (row < N) hb[(size_t)row * 64 + (n << 4) + l15] = f2bf(acc[n][q]);
    }
  }
  __syncthreads();
  if (tid == 0) atomicAdd(flag, 1);
}

// ---------- aggregate + self + BN: 1 node/32-lane group, 4 EDGES PER STEP ----------
// 8 lanes x uint4 (16B) cover a 128B hb row; 32 lanes service 4 edges per VMEM
// instruction -> gather/cnt/LDS instruction counts halve vs round 12. Tail lanes
// clamp to node 0's row (stays hot in L1/L2, near-free). Reduce via shfl_xor 8,16.
#define ACC8(u, s)                                            \
  a0 = fmaf(s, bfLO(u.x), a0); a1 = fmaf(s, bfHI(u.x), a1);   \
  a2 = fmaf(s, bfLO(u.y), a2); a3 = fmaf(s, bfHI(u.y), a3);   \
  a4 = fmaf(s, bfLO(u.z), a4); a5 = fmaf(s, bfHI(u.z), a5);   \
  a6 = fmaf(s, bfLO(u.w), a6); a7 = fmaf(s, bfHI(u.w), a7);

__global__ __launch_bounds__(256) void k_agg(const int* __restrict__ cnt,
                                             const int* __restrict__ ell_t,
                                             const uint4* __restrict__ hb128,
                                             const float* __restrict__ gamma,
                                             const float* __restrict__ beta,
                                             const float* __restrict__ mean,
                                             const float* __restrict__ var,
                                             float* __restrict__ out, int N) {
  __shared__ int lds_dst[CAP * ABLK];   // [p][j], 1 KB

  int tid = threadIdx.x;
  int node0 = blockIdx.x * ABLK;

  // one staging read per thread: p = tid>>3, j = tid&7 (CAP*ABLK == 256)
  {
    int j = tid & (ABLK - 1);
    int p = tid >> 3;
    int n = node0 + j;
    lds_dst[p * ABLK + j] = (n < N) ? ell_t[(size_t)p * N + n] : 0;
  }

  int hw = tid >> 5;          // node within block
  int lane32 = tid & 31;
  int sl = lane32 & 7;        // 16B chunk index (features 8sl..8sl+7)
  int eg = lane32 >> 3;       // edge subgroup 0..3
  int node = node0 + hw;

  // BN params for features 8sl..8sl+7; fold to o = r*gs + bp
  float4 gA = *(const float4*)&gamma[sl * 8];
  float4 gB = *(const float4*)&gamma[sl * 8 + 4];
  float4 bA = *(const float4*)&beta[sl * 8];
  float4 bB = *(const float4*)&beta[sl * 8 + 4];
  float4 mA = *(const float4*)&mean[sl * 8];
  float4 mB = *(const float4*)&mean[sl * 8 + 4];
  float4 vA = *(const float4*)&var[sl * 8];
  float4 vB = *(const float4*)&var[sl * 8 + 4];
  float gs0 = gA.x * rsqrtf(vA.x + BN_EPS), bp0 = bA.x - mA.x * gs0;
  float gs1 = gA.y * rsqrtf(vA.y + BN_EPS), bp1 = bA.y - mA.y * gs1;
  float gs2 = gA.z * rsqrtf(vA.z + BN_EPS), bp2 = bA.z - mA.z * gs2;
  float gs3 = gA.w * rsqrtf(vA.w + BN_EPS), bp3 = bA.w - mA.w * gs3;
  float gs4 = gB.x * rsqrtf(vB.x + BN_EPS), bp4 = bB.x - mB.x * gs4;
  float gs5 = gB.y * rsqrtf(vB.y + BN_EPS), bp5 = bB.y - mB.y * gs5;
  float gs6 = gB.z * rsqrtf(vB.z + BN_EPS), bp6 = bB.z - mB.z * gs6;
  float gs7 = gB.w * rsqrtf(vB.w + BN_EPS), bp7 = bB.w - mB.w * gs7;

  __syncthreads();
  if (node >= N) return;

  int c0 = cnt[node];                           // 32-lane-uniform, L2-resident
  int c = (c0 < CAP) ? c0 : CAP;
  uint4 us = hb128[(size_t)node * 8 + sl];      // self row, issue early

  float a0 = 0.f, a1 = 0.f, a2 = 0.f, a3 = 0.f;
  float a4 = 0.f, a5 = 0.f, a6 = 0.f, a7 = 0.f;

  int nst = (c + 3) >> 2;
  int st = 0;
  for (; st + 2 <= nst; st += 2) {              // 8 edges per iteration
    int e0 = 4 * st + eg, e1 = 4 * (st + 1) + eg;
    int dr0 = (e0 < c) ? lds_dst[e0 * ABLK + hw] : 0;
    int dr1 = (e1 < c) ? lds_dst[e1 * ABLK + hw] : 0;
    float v0 = (e0 < c) ? 1.f : 0.f;
    float v1 = (e1 < c) ? 1.f : 0.f;
    int d0 = ((unsigned)dr0 < (unsigned)N) ? dr0 : 0;
    int d1 = ((unsigned)dr1 < (unsigned)N) ? dr1 : 0;
    int c0_ = cnt[d0], c1_ = cnt[d1];
    uint4 u0 = hb128[(size_t)d0 * 8 + sl];
    uint4 u1 = hb128[(size_t)d1 * 8 + sl];
    float s0 = v0 * rsqrtf((float)((c0_ > 0) ? c0_ : 1));
    float s1 = v1 * rsqrtf((float)((c1_ > 0) ? c1_ : 1));
    ACC8(u0, s0);
    ACC8(u1, s1);
  }
  for (; st < nst; ++st) {
    int e = 4 * st + eg;
    int dr = (e < c) ? lds_dst[e * ABLK + hw] : 0;
    float v = (e < c) ? 1.f : 0.f;
    int d = ((unsigned)dr < (unsigned)N) ? dr : 0;
    int cq = cnt[d];
    uint4 u = hb128[(size_t)d * 8 + sl];
    float s = v * rsqrtf((float)((cq > 0) ? cq : 1));
    ACC8(u, s);
  }

  // combine the 4 edge subgroups (xor 8 and 16 stay within the 32-lane group)
  a0 += __shfl_xor(a0, 8);  a0 += __shfl_xor(a0, 16);
  a1 += __shfl_xor(a1, 8);  a1 += __shfl_xor(a1, 16);
  a2 += __shfl_xor(a2, 8);  a2 += __shfl_xor(a2, 16);
  a3 += __shfl_xor(a3, 8);  a3 += __shfl_xor(a3, 16);
  a4 += __shfl_xor(a4, 8);  a4 += __shfl_xor(a4, 16);
  a5 += __shfl_xor(a5, 8);  a5 += __shfl_xor(a5, 16);
  a6 += __shfl_xor(a6, 8);  a6 += __shfl_xor(a6, 16);
  a7 += __shfl_xor(a7, 8);  a7 += __shfl_xor(a7, 16);

  if (eg == 0) {
    float degf = (float)c0;
    float isd = rsqrtf((float)((c0 > 0) ? c0 : 1));
    float r0 = 0.5f * (isd * a0 + degf * bfLO(us.x));
    float r1 = 0.5f * (isd * a1 + degf * bfHI(us.x));
    float r2 = 0.5f * (isd * a2 + degf * bfLO(us.y));
    float r3 = 0.5f * (isd * a3 + degf * bfHI(us.y));
    float r4 = 0.5f * (isd * a4 + degf * bfLO(us.z));
    float r5 = 0.5f * (isd * a5 + degf * bfHI(us.z));
    float r6 = 0.5f * (isd * a6 + degf * bfLO(us.w));
    float r7 = 0.5f * (isd * a7 + degf * bfHI(us.w));
    float4 oA = make_float4(r0 * gs0 + bp0, r1 * gs1 + bp1,
                            r2 * gs2 + bp2, r3 * gs3 + bp3);
    float4 oB = make_float4(r4 * gs4 + bp4, r5 * gs5 + bp5,
                            r6 * gs6 + bp6, r7 * gs7 + bp7);
    *(float4*)&out[(size_t)node * 64 + sl * 8] = oA;      // 8 lanes x 32B = 256B row
    *(float4*)&out[(size_t)node * 64 + sl * 8 + 4] = oB;
  }
}

extern "C" void kernel_launch(void* const* d_in, const int* in_sizes, int n_in,
                              void* d_out, int out_size, void* d_ws, size_t ws_size,
                              hipStream_t stream) {
  const float* X     = (const float*)d_in[0];
  const float* W     = (const float*)d_in[1];
  const float* B     = (const float*)d_in[2];
  const float* gamma = (const float*)d_in[3];
  const float* beta  = (const float*)d_in[4];
  const float* mean  = (const float*)d_in[5];
  const float* var   = (const float*)d_in[6];
  const int2*  ei    = (const int2*)d_in[7];

  int N = in_sizes[0] / 128;
  int E = in_sizes[7] / 2;
  float* out = (float*)d_out;

  // workspace: hb (N*64 bf16 = 12.8MB) | ell_t (N*CAP int = 12.8MB) | cnt (N int) | flag
  unsigned short* hb   = (unsigned short*)d_ws;
  int*            ell  = (int*)(hb + (size_t)N * 64);
  int*            cnt  = ell + (size_t)N * CAP;
  int*            flag = cnt + N;

  (void)hipMemsetAsync(cnt, 0, ((size_t)N + 1) * sizeof(int), stream);

  int Gg = (N + 63) / 64;                       // gemm tiles (bids [0, Gg))
  int gemmPad = (Gg + 7) & ~7;                  // scatter base, multiple of 8
  int nsegs = (E + SEGE - 1) / SEGE;            // scatter segments (x8 partitions)
  int grid = gemmPad + nsegs * 8;
  k_fused<<<grid, 256, 0, stream>>>(X, W, B, hb, N, Gg, ei, cnt, ell, E, gemmPad, flag);

  int Ga = (N + ABLK - 1) / ABLK;               // agg blocks (8 nodes each)
  k_agg<<<Ga, 256, 0, stream>>>(cnt, ell, (const uint4*)hb,
                                gamma, beta, mean, var, out, N);
}

// Round 14
// 175.156 us; speedup vs baseline: 1.8088x; 1.8088x over previous
//
#include <hip/hip_runtime.h>

#define BN_EPS 0.001f
#define CAP 32    // deg = 1 + Poisson(~9); P(deg >= 32) ~ 1e-22 -> safe
#define NPART 8   // node partitions, bound to XCD via p = blockIdx&7 (heuristic)
#define SEGE 4096 // edges per scatter segment (256 threads x 16 edges)
#define ABLK 8    // agg: nodes per block (1 node per 32-lane group)

typedef __attribute__((ext_vector_type(8))) short bf16x8;
typedef __attribute__((ext_vector_type(4))) float f32x4;

__device__ __forceinline__ unsigned short f2bf(float f) {
  unsigned u = __float_as_uint(f);
  u += 0x7fffu + ((u >> 16) & 1u);
  return (unsigned short)(u >> 16);
}
__device__ __forceinline__ float bfLO(unsigned u) { return __uint_as_float(u << 16); }
__device__ __forceinline__ float bfHI(unsigned u) { return __uint_as_float(u & 0xffff0000u); }

// ---------- FUSED: XCD-bound partitioned scatter + MFMA gemm (round-12, 171us best) ----------
// Write-amp post-mortem (rounds 5/9/13): ~33MB excess WRITE is intrinsic to 1M
// device-scope atomics + random 4B stores (atomic write-throughs are not L2-
// coalescible across XCDs); transpose, NT hints, and temporal gemm/scatter
// separation all refuted as fixes. ~52us is this scatter's structural floor.
__global__ __launch_bounds__(256) void k_fused(
    const float* __restrict__ X, const float* __restrict__ W,
    const float* __restrict__ B, unsigned short* __restrict__ hb, int N, int Gg,
    const int2* __restrict__ ei, int* __restrict__ cnt,
    int* __restrict__ ell_t, int E) {
  __shared__ float WtF[4096];  // 16 KB: Wt[col][k] bf16, XOR-swizzled

  int bid = blockIdx.x;
  int tid = threadIdx.x;
  int gid = bid >> 4;
  int slot = bid & 15;

  if (slot < 8) {
    // ----- scatter role: partition p = bid&7 (XCD-bound), segment = gid -----
    int p = slot;
    int lo = (int)((long long)p * N / NPART);
    int hi = (int)((long long)(p + 1) * N / NPART);
    const int4* e4 = (const int4*)ei;
    int n4 = E >> 1;
    int base4 = gid * (SEGE / 2);
    #pragma unroll
    for (int i = 0; i < 8; ++i) {
      int q = base4 + i * 256 + tid;
      if (q < n4) {
        int4 v = e4[q];                   // 2 edges, coalesced
        if (v.x >= lo && v.x < hi) {
          int pos = atomicAdd(&cnt[v.x], 1);
          if (pos < CAP) ell_t[(size_t)pos * N + v.x] = v.y;
        }
        if (v.z >= lo && v.z < hi) {
          int pos = atomicAdd(&cnt[v.z], 1);
          if (pos < CAP) ell_t[(size_t)pos * N + v.z] = v.w;
        }
      }
    }
    if ((E & 1) && gid == 0 && tid == 0) {
      int2 sd = ei[E - 1];
      if (sd.x >= lo && sd.x < hi) {
        int pos = atomicAdd(&cnt[sd.x], 1);
        if (pos < CAP) ell_t[(size_t)pos * N + sd.x] = sd.y;
      }
    }
    return;
  }

  // ----- gemm role: hb = bf16(X@W + b) via MFMA, 64 rows x 64 cols per block -----
  int tile = gid * 8 + (slot - 8);
  if (tile >= Gg) return;

  char* Wt = (char*)WtF;
  const float4* W4 = (const float4*)W;
  for (int i = tid; i < 2048; i += 256) {
    float4 v = W4[i];
    int k = i >> 4;
    int col0 = (i & 15) << 2;
    int kb2 = k << 1;
    *(unsigned short*)(Wt + (((col0 + 0) << 8) | (kb2 ^ (((col0 + 0) & 7) << 4)))) = f2bf(v.x);
    *(unsigned short*)(Wt + (((col0 + 1) << 8) | (kb2 ^ (((col0 + 1) & 7) << 4)))) = f2bf(v.y);
    *(unsigned short*)(Wt + (((col0 + 2) << 8) | (kb2 ^ (((col0 + 2) & 7) << 4)))) = f2bf(v.z);
    *(unsigned short*)(Wt + (((col0 + 3) << 8) | (kb2 ^ (((col0 + 3) & 7) << 4)))) = f2bf(v.w);
  }
  __syncthreads();

  int lane = tid & 63;
  int w = tid >> 6;
  int l15 = lane & 15;
  int lk = lane >> 4;

  int row0 = tile * 64;
  int rA = row0 + w * 16 + l15;
  bool rowok = rA < N;
  const float* xp = X + (size_t)rA * 128 + (lk << 3);

  f32x4 acc[4];
  #pragma unroll
  for (int n = 0; n < 4; ++n) {
    float bv = B[(n << 4) + l15];
    acc[n] = (f32x4){bv, bv, bv, bv};
  }

  #pragma unroll
  for (int kb = 0; kb < 4; ++kb) {
    bf16x8 af = {0, 0, 0, 0, 0, 0, 0, 0};
    if (rowok) {
      float4 x0 = *(const float4*)(xp + kb * 32);
      float4 x1 = *(const float4*)(xp + kb * 32 + 4);
      af[0] = (short)f2bf(x0.x); af[1] = (short)f2bf(x0.y);
      af[2] = (short)f2bf(x0.z); af[3] = (short)f2bf(x0.w);
      af[4] = (short)f2bf(x1.x); af[5] = (short)f2bf(x1.y);
      af[6] = (short)f2bf(x1.z); af[7] = (short)f2bf(x1.w);
    }
    int kbyte = (kb << 6) | (lk << 4);
    #pragma unroll
    for (int n = 0; n < 4; ++n) {
      int col = (n << 4) + l15;
      bf16x8 bfr = *(const bf16x8*)(Wt + ((col << 8) | (kbyte ^ ((col & 7) << 4))));
      acc[n] = __builtin_amdgcn_mfma_f32_16x16x32_bf16(af, bfr, acc[n], 0, 0, 0);
    }
  }

  // C/D layout (verified m89/m91): col = lane&15, row = (lane>>4)*4 + reg
  int rbase = row0 + w * 16 + (lk << 2);
  #pragma unroll
  for (int n = 0; n < 4; ++n) {
    #pragma unroll
    for (int q = 0; q < 4; ++q) {
      int row = rbase + q;
      if (row < N) hb[(size_t)row * 64 + (n << 4) + l15] = f2bf(acc[n][q]);
    }
  }
}

// ---------- aggregate + self + BN: 1 node/32-lane group, 4 EDGES PER STEP ----------
// (round-13 agg, verified; ~40us) 8 lanes x uint4 cover a 128B hb row; 32 lanes
// service 4 edges per VMEM instruction. Reduce via shfl_xor 8,16.
#define ACC8(u, s)                                            \
  a0 = fmaf(s, bfLO(u.x), a0); a1 = fmaf(s, bfHI(u.x), a1);   \
  a2 = fmaf(s, bfLO(u.y), a2); a3 = fmaf(s, bfHI(u.y), a3);   \
  a4 = fmaf(s, bfLO(u.z), a4); a5 = fmaf(s, bfHI(u.z), a5);   \
  a6 = fmaf(s, bfLO(u.w), a6); a7 = fmaf(s, bfHI(u.w), a7);

__global__ __launch_bounds__(256) void k_agg(const int* __restrict__ cnt,
                                             const int* __restrict__ ell_t,
                                             const uint4* __restrict__ hb128,
                                             const float* __restrict__ gamma,
                                             const float* __restrict__ beta,
                                             const float* __restrict__ mean,
                                             const float* __restrict__ var,
                                             float* __restrict__ out, int N) {
  __shared__ int lds_dst[CAP * ABLK];   // [p][j], 1 KB

  int tid = threadIdx.x;
  int node0 = blockIdx.x * ABLK;

  // one staging read per thread: p = tid>>3, j = tid&7 (CAP*ABLK == 256)
  {
    int j = tid & (ABLK - 1);
    int p = tid >> 3;
    int n = node0 + j;
    lds_dst[p * ABLK + j] = (n < N) ? ell_t[(size_t)p * N + n] : 0;
  }

  int hw = tid >> 5;          // node within block
  int lane32 = tid & 31;
  int sl = lane32 & 7;        // 16B chunk index (features 8sl..8sl+7)
  int eg = lane32 >> 3;       // edge subgroup 0..3
  int node = node0 + hw;

  // BN params for features 8sl..8sl+7; fold to o = r*gs + bp
  float4 gA = *(const float4*)&gamma[sl * 8];
  float4 gB = *(const float4*)&gamma[sl * 8 + 4];
  float4 bA = *(const float4*)&beta[sl * 8];
  float4 bB = *(const float4*)&beta[sl * 8 + 4];
  float4 mA = *(const float4*)&mean[sl * 8];
  float4 mB = *(const float4*)&mean[sl * 8 + 4];
  float4 vA = *(const float4*)&var[sl * 8];
  float4 vB = *(const float4*)&var[sl * 8 + 4];
  float gs0 = gA.x * rsqrtf(vA.x + BN_EPS), bp0 = bA.x - mA.x * gs0;
  float gs1 = gA.y * rsqrtf(vA.y + BN_EPS), bp1 = bA.y - mA.y * gs1;
  float gs2 = gA.z * rsqrtf(vA.z + BN_EPS), bp2 = bA.z - mA.z * gs2;
  float gs3 = gA.w * rsqrtf(vA.w + BN_EPS), bp3 = bA.w - mA.w * gs3;
  float gs4 = gB.x * rsqrtf(vB.x + BN_EPS), bp4 = bB.x - mB.x * gs4;
  float gs5 = gB.y * rsqrtf(vB.y + BN_EPS), bp5 = bB.y - mB.y * gs5;
  float gs6 = gB.z * rsqrtf(vB.z + BN_EPS), bp6 = bB.z - mB.z * gs6;
  float gs7 = gB.w * rsqrtf(vB.w + BN_EPS), bp7 = bB.w - mB.w * gs7;

  __syncthreads();
  if (node >= N) return;

  int c0 = cnt[node];                           // 32-lane-uniform, L2-resident
  int c = (c0 < CAP) ? c0 : CAP;
  uint4 us = hb128[(size_t)node * 8 + sl];      // self row, issue early

  float a0 = 0.f, a1 = 0.f, a2 = 0.f, a3 = 0.f;
  float a4 = 0.f, a5 = 0.f, a6 = 0.f, a7 = 0.f;

  int nst = (c + 3) >> 2;
  int st = 0;
  for (; st + 2 <= nst; st += 2) {              // 8 edges per iteration
    int e0 = 4 * st + eg, e1 = 4 * (st + 1) + eg;
    int dr0 = (e0 < c) ? lds_dst[e0 * ABLK + hw] : 0;
    int dr1 = (e1 < c) ? lds_dst[e1 * ABLK + hw] : 0;
    float v0 = (e0 < c) ? 1.f : 0.f;
    float v1 = (e1 < c) ? 1.f : 0.f;
    int d0 = ((unsigned)dr0 < (unsigned)N) ? dr0 : 0;
    int d1 = ((unsigned)dr1 < (unsigned)N) ? dr1 : 0;
    int c0_ = cnt[d0], c1_ = cnt[d1];
    uint4 u0 = hb128[(size_t)d0 * 8 + sl];
    uint4 u1 = hb128[(size_t)d1 * 8 + sl];
    float s0 = v0 * rsqrtf((float)((c0_ > 0) ? c0_ : 1));
    float s1 = v1 * rsqrtf((float)((c1_ > 0) ? c1_ : 1));
    ACC8(u0, s0);
    ACC8(u1, s1);
  }
  for (; st < nst; ++st) {
    int e = 4 * st + eg;
    int dr = (e < c) ? lds_dst[e * ABLK + hw] : 0;
    float v = (e < c) ? 1.f : 0.f;
    int d = ((unsigned)dr < (unsigned)N) ? dr : 0;
    int cq = cnt[d];
    uint4 u = hb128[(size_t)d * 8 + sl];
    float s = v * rsqrtf((float)((cq > 0) ? cq : 1));
    ACC8(u, s);
  }

  // combine the 4 edge subgroups (xor 8 and 16 stay within the 32-lane group)
  a0 += __shfl_xor(a0, 8);  a0 += __shfl_xor(a0, 16);
  a1 += __shfl_xor(a1, 8);  a1 += __shfl_xor(a1, 16);
  a2 += __shfl_xor(a2, 8);  a2 += __shfl_xor(a2, 16);
  a3 += __shfl_xor(a3, 8);  a3 += __shfl_xor(a3, 16);
  a4 += __shfl_xor(a4, 8);  a4 += __shfl_xor(a4, 16);
  a5 += __shfl_xor(a5, 8);  a5 += __shfl_xor(a5, 16);
  a6 += __shfl_xor(a6, 8);  a6 += __shfl_xor(a6, 16);
  a7 += __shfl_xor(a7, 8);  a7 += __shfl_xor(a7, 16);

  if (eg == 0) {
    float degf = (float)c0;
    float isd = rsqrtf((float)((c0 > 0) ? c0 : 1));
    float r0 = 0.5f * (isd * a0 + degf * bfLO(us.x));
    float r1 = 0.5f * (isd * a1 + degf * bfHI(us.x));
    float r2 = 0.5f * (isd * a2 + degf * bfLO(us.y));
    float r3 = 0.5f * (isd * a3 + degf * bfHI(us.y));
    float r4 = 0.5f * (isd * a4 + degf * bfLO(us.z));
    float r5 = 0.5f * (isd * a5 + degf * bfHI(us.z));
    float r6 = 0.5f * (isd * a6 + degf * bfLO(us.w));
    float r7 = 0.5f * (isd * a7 + degf * bfHI(us.w));
    float4 oA = make_float4(r0 * gs0 + bp0, r1 * gs1 + bp1,
                            r2 * gs2 + bp2, r3 * gs3 + bp3);
    float4 oB = make_float4(r4 * gs4 + bp4, r5 * gs5 + bp5,
                            r6 * gs6 + bp6, r7 * gs7 + bp7);
    *(float4*)&out[(size_t)node * 64 + sl * 8] = oA;      // 8 lanes x 32B = 256B row
    *(float4*)&out[(size_t)node * 64 + sl * 8 + 4] = oB;
  }
}

extern "C" void kernel_launch(void* const* d_in, const int* in_sizes, int n_in,
                              void* d_out, int out_size, void* d_ws, size_t ws_size,
                              hipStream_t stream) {
  const float* X     = (const float*)d_in[0];
  const float* W     = (const float*)d_in[1];
  const float* B     = (const float*)d_in[2];
  const float* gamma = (const float*)d_in[3];
  const float* beta  = (const float*)d_in[4];
  const float* mean  = (const float*)d_in[5];
  const float* var   = (const float*)d_in[6];
  const int2*  ei    = (const int2*)d_in[7];

  int N = in_sizes[0] / 128;
  int E = in_sizes[7] / 2;
  float* out = (float*)d_out;

  // workspace: hb (N*64 bf16 = 12.8MB) | ell_t (N*CAP int = 12.8MB) | cnt (N int)
  unsigned short* hb  = (unsigned short*)d_ws;
  int*            ell = (int*)(hb + (size_t)N * 64);
  int*            cnt = ell + (size_t)N * CAP;

  (void)hipMemsetAsync(cnt, 0, (size_t)N * sizeof(int), stream);

  int Gg = (N + 63) / 64;                       // gemm tiles
  int nsegs = (E + SEGE - 1) / SEGE;            // scatter segments (x8 partitions)
  int ngg = (Gg + 7) / 8;                       // gemm groups
  int ngroups = (nsegs > ngg) ? nsegs : ngg;
  k_fused<<<ngroups * 16, 256, 0, stream>>>(X, W, B, hb, N, Gg, ei, cnt, ell, E);

  int Ga = (N + ABLK - 1) / ABLK;               // agg blocks (8 nodes each)
  k_agg<<<Ga, 256, 0, stream>>>(cnt, ell, (const uint4*)hb,
                                gamma, beta, mean, var, out, N);
}